// Round 13
// baseline (86.307 us; speedup 1.0000x reference)
//
#include <hip/hip_runtime.h>

// FeatureEmbedder: out[b, f*64+d] = relu(x[b,f] * W[f,d] + b[f,d])
// x: [16384, 128] f32, W: [128, 64] f32, b: [128, 64] f32
// out: [16384, 8192] f32  (512 MB -> HBM-write-bound)
//
// R13: R12 (nt x block-linear, 85.3 us) minus the barrier drains. R12's 8
// __syncthreads each forced s_waitcnt vmcnt(0), fully draining the nt-store
// FIFO (8 pipeline restarts ~= the 7 us gap to fill rate). Changes, all
// serving "never drain the store FIFO":
//  1) 64-row slabs (2 x 32 KB LDS double buffer) -> 4 phases, not 8.
//  2) raw s_waitcnt lgkmcnt(0) + __builtin_amdgcn_s_barrier() instead of
//     __syncthreads(): the barrier only orders LDS (prefetch visibility +
//     WAR on the buffer being overwritten) -- global nt stores stay in
//     flight across it (T3/T4 counted-vmcnt principle).
//  3) T14 issue-early/write-late staging: slab s+1's global loads issue
//     BEFORE slab s's 128 stores; reg->ds_write after. The ds_write's
//     vmcnt wait is then satisfied by in-order retirement (loads are
//     oldest in the FIFO) without stalling the store stream.

#define BATCH 16384
#define NFEAT 128
#define EMBD  64
#define ROW4  (NFEAT * EMBD / 4)   // 2048 float4 per output row

typedef float vfloat4 __attribute__((ext_vector_type(4)));

__global__ __launch_bounds__(1024) void feature_embed_kernel(
    const vfloat4* __restrict__ x4,
    const vfloat4* __restrict__ W4,
    const vfloat4* __restrict__ B4,
    vfloat4* __restrict__ out4) {

    __shared__ float xs[2][64 * NFEAT];   // 2 x 32 KB slab buffers (64 rows)

    const int tid = threadIdx.x;          // 0..1023
    const int b   = blockIdx.x;           // 0..63

    // Thread's columns: col4 = j*1024 + tid, j = 0..1. Hoist W/b.
    vfloat4 wv[2], bv[2];
    wv[0] = W4[tid];        wv[1] = W4[1024 + tid];
    bv[0] = B4[tid];        bv[1] = B4[1024 + tid];

    // Block owns x rows [256b, 256b+256) = 8192 float4: 4 slabs x 2048.
    const vfloat4* xb = x4 + b * (256 * NFEAT / 4);

    // Stage slab 0 (2 float4/thread, coalesced).
    {
        vfloat4* dst = (vfloat4*)xs[0];
        dst[tid]        = xb[tid];
        dst[1024 + tid] = xb[1024 + tid];
    }
    asm volatile("s_waitcnt lgkmcnt(0)" ::: "memory");
    __builtin_amdgcn_s_barrier();

    const int fs = tid >> 4;              // feature sub-index, 0..63
    vfloat4* outb = out4 + b * 256 * ROW4;  // this block's 8 MB region

    for (int s = 0; s < 4; ++s) {
        // (3) Issue next slab's global loads FIRST (oldest FIFO entries;
        // they retire during the sweep below, ahead of the stores).
        vfloat4 pf0, pf1;
        if (s < 3) {
            pf0 = xb[(s + 1) * 2048 + tid];
            pf1 = xb[(s + 1) * 2048 + 1024 + tid];
        }

        const float* xsl = xs[s & 1];
        vfloat4* outs = outb + s * 64 * ROW4;

        // Sweep: 64 rows x 32 KB, linear nt-store stream (128 stores/thread).
        #pragma unroll 4
        for (int r = 0; r < 64; ++r) {
            const float* xr = xsl + r * NFEAT;
            vfloat4* outr = outs + r * ROW4 + tid;
            #pragma unroll
            for (int j = 0; j < 2; ++j) {
                const float xv = xr[j * 64 + fs];   // ds_read broadcast
                vfloat4 o;
                o.x = fmaxf(fmaf(xv, wv[j].x, bv[j].x), 0.0f);
                o.y = fmaxf(fmaf(xv, wv[j].y, bv[j].y), 0.0f);
                o.z = fmaxf(fmaf(xv, wv[j].z, bv[j].z), 0.0f);
                o.w = fmaxf(fmaf(xv, wv[j].w, bv[j].w), 0.0f);
                __builtin_nontemporal_store(o, &outr[j * 1024]);
            }
        }

        // (3) Write-late: park the prefetched slab in the other buffer.
        if (s < 3) {
            vfloat4* dst = (vfloat4*)xs[(s + 1) & 1];
            dst[tid]        = pf0;
            dst[1024 + tid] = pf1;
        }
        // (2) LDS-only barrier: ds ops drained, nt stores stay in flight.
        asm volatile("s_waitcnt lgkmcnt(0)" ::: "memory");
        __builtin_amdgcn_s_barrier();
    }
}

extern "C" void kernel_launch(void* const* d_in, const int* in_sizes, int n_in,
                              void* d_out, int out_size, void* d_ws, size_t ws_size,
                              hipStream_t stream) {
    const vfloat4* x4 = (const vfloat4*)d_in[0];
    const vfloat4* W4 = (const vfloat4*)d_in[1];
    const vfloat4* B4 = (const vfloat4*)d_in[2];
    vfloat4* out4     = (vfloat4*)d_out;

    // 64 blocks x 1024 threads; block b writes rows [256b, 256b+256) linearly.
    feature_embed_kernel<<<64, 1024, 0, stream>>>(x4, W4, B4, out4);
}